// Round 1
// baseline (82.030 us; speedup 1.0000x reference)
//
#include <hip/hip_runtime.h>
#include <cstdint>

typedef __bf16 bf16x8 __attribute__((ext_vector_type(8)));
typedef float f32x4 __attribute__((ext_vector_type(4)));
typedef unsigned short u16;

#define NROWS 4096
#define DIM 512
#define ZROWS 8192
#define BM 128
#define BK 64
#define NTILES 64  /* 8192/128 */
#define NBLOCKS 2080 /* 64*65/2 upper-triangular tile pairs */

// ---------------- kernel 1: f32 -> bf16 + row norms (from bf16-rounded values) ----
__global__ __launch_bounds__(256) void prep_kernel(const float* __restrict__ lbl,
                                                   const float* __restrict__ pred,
                                                   u16* __restrict__ zb,
                                                   float* __restrict__ xnorm) {
    const int w = threadIdx.x >> 6;
    const int l = threadIdx.x & 63;
    const int row = blockIdx.x * 4 + w;
    const float* src = (row < NROWS) ? (lbl + (size_t)row * DIM)
                                     : (pred + (size_t)(row - NROWS) * DIM);
    const float4 v0 = *(const float4*)(src + l * 8);
    const float4 v1 = *(const float4*)(src + l * 8 + 4);
    float f[8] = {v0.x, v0.y, v0.z, v0.w, v1.x, v1.y, v1.z, v1.w};
    uint32_t pk[4];
    float nrm = 0.f;
#pragma unroll
    for (int j = 0; j < 4; ++j) {
        uint32_t b0 = __float_as_uint(f[2 * j]);
        uint32_t b1 = __float_as_uint(f[2 * j + 1]);
        uint32_t r0 = (b0 + 0x7fffu + ((b0 >> 16) & 1u)) >> 16;  // RNE to bf16
        uint32_t r1 = (b1 + 0x7fffu + ((b1 >> 16) & 1u)) >> 16;
        pk[j] = r0 | (r1 << 16);
        float fb0 = __uint_as_float(r0 << 16);
        float fb1 = __uint_as_float(r1 << 16);
        nrm += fb0 * fb0 + fb1 * fb1;
    }
    *(uint4*)(zb + (size_t)row * DIM + l * 8) = make_uint4(pk[0], pk[1], pk[2], pk[3]);
#pragma unroll
    for (int off = 32; off; off >>= 1) nrm += __shfl_xor(nrm, off);
    if (l == 0) xnorm[row] = nrm;
}

// ---------------- kernel 2: Z Z^T tile GEMM + fused exp/sign/reduce epilogue ------
__global__ __launch_bounds__(256) void mmd_gemm_kernel(const u16* __restrict__ zb,
                                                       const float* __restrict__ xnorm,
                                                       float* __restrict__ partials) {
    __shared__ u16 ldsA[BM * BK];  // [128][64] bf16, linear (global_load_lds dest)
    __shared__ u16 ldsB[BM * BK];
    __shared__ float red[4];

    // decode upper-triangular (bm <= bn) tile pair
    int bm = 0, rem = blockIdx.x;
    while (rem >= (NTILES - bm)) { rem -= (NTILES - bm); ++bm; }
    const int bn = bm + rem;

    const int tid = threadIdx.x;
    const int w = tid >> 6;
    const int l = tid & 63;
    const int warpM = w >> 1, warpN = w & 1;

    const int rowA0 = bm * BM;
    const int rowB0 = bn * BM;

    f32x4 acc[4][4];
#pragma unroll
    for (int m = 0; m < 4; ++m)
#pragma unroll
        for (int n = 0; n < 4; ++n) acc[m][n] = (f32x4){0.f, 0.f, 0.f, 0.f};

    for (int kt = 0; kt < DIM / BK; ++kt) {
        __syncthreads();  // previous compute done before overwriting LDS
#pragma unroll
        for (int it = 0; it < 4; ++it) {
            const int r = it * 32 + w * 8 + (l >> 3);
            const int cb = (l & 7) * 16;  // byte offset within 128B row-chunk
            const char* gA = (const char*)zb + ((size_t)(rowA0 + r) * DIM + kt * BK) * 2 + cb;
            const char* gB = (const char*)zb + ((size_t)(rowB0 + r) * DIM + kt * BK) * 2 + cb;
            char* lA = (char*)ldsA + it * 4096 + w * 1024 + l * 16;
            char* lB = (char*)ldsB + it * 4096 + w * 1024 + l * 16;
            __builtin_amdgcn_global_load_lds((const __attribute__((address_space(1))) void*)gA,
                                             (__attribute__((address_space(3))) void*)lA, 16, 0, 0);
            __builtin_amdgcn_global_load_lds((const __attribute__((address_space(1))) void*)gB,
                                             (__attribute__((address_space(3))) void*)lB, 16, 0, 0);
        }
        __syncthreads();  // compiler drains vmcnt before barrier
#pragma unroll
        for (int kk = 0; kk < 2; ++kk) {
            bf16x8 af[4], bg[4];
            const int kof = kk * 32 + (l >> 4) * 8;
#pragma unroll
            for (int m = 0; m < 4; ++m) {
                const int r = warpM * 64 + m * 16 + (l & 15);
                af[m] = *(const bf16x8*)((const char*)ldsA + r * 128 + kof * 2);
            }
#pragma unroll
            for (int n = 0; n < 4; ++n) {
                const int r = warpN * 64 + n * 16 + (l & 15);
                bg[n] = *(const bf16x8*)((const char*)ldsB + r * 128 + kof * 2);
            }
#pragma unroll
            for (int m = 0; m < 4; ++m)
#pragma unroll
                for (int n = 0; n < 4; ++n)
                    acc[m][n] = __builtin_amdgcn_mfma_f32_16x16x32_bf16(af[m], bg[n], acc[m][n], 0, 0, 0);
        }
    }

    // epilogue: dist = xi + xj - 2*c ; term = exp(-dist/2) = exp2(-dist/(2 ln2))
    const int baseI = rowA0 + warpM * 64;
    const int baseJ = rowB0 + warpN * 64;
    float xi[16], si[16];
#pragma unroll
    for (int m = 0; m < 4; ++m)
#pragma unroll
        for (int r = 0; r < 4; ++r) {
            int i = baseI + m * 16 + (l >> 4) * 4 + r;
            xi[m * 4 + r] = xnorm[i];
            si[m * 4 + r] = (i < NROWS) ? 1.f : -1.f;
        }
    float xj[4], sj[4];
#pragma unroll
    for (int n = 0; n < 4; ++n) {
        int j = baseJ + n * 16 + (l & 15);
        xj[n] = xnorm[j];
        sj[n] = (j < NROWS) ? 1.f : -1.f;
    }
    float local = 0.f;
#pragma unroll
    for (int m = 0; m < 4; ++m)
#pragma unroll
        for (int n = 0; n < 4; ++n)
#pragma unroll
            for (int r = 0; r < 4; ++r) {
                float d = xi[m * 4 + r] + xj[n] - 2.f * acc[m][n][r];
                local += si[m * 4 + r] * sj[n] * exp2f(-0.72134752f * d);
            }
    if (bm != bn) local *= 2.f;  // off-diagonal tiles counted twice by symmetry
#pragma unroll
    for (int off = 32; off; off >>= 1) local += __shfl_xor(local, off);
    if (l == 0) red[w] = local;
    __syncthreads();
    if (tid == 0) partials[blockIdx.x] = red[0] + red[1] + red[2] + red[3];
}

// ---------------- kernel 3: deterministic final reduce ---------------------------
__global__ __launch_bounds__(256) void reduce_kernel(const float* __restrict__ partials,
                                                     float* __restrict__ out, int n) {
    __shared__ float red[4];
    float s = 0.f;
    for (int i = threadIdx.x; i < n; i += 256) s += partials[i];
#pragma unroll
    for (int off = 32; off; off >>= 1) s += __shfl_xor(s, off);
    if ((threadIdx.x & 63) == 0) red[threadIdx.x >> 6] = s;
    __syncthreads();
    if (threadIdx.x == 0)
        out[0] = (red[0] + red[1] + red[2] + red[3]) * (1.f / 16777216.f);  // / 4096^2
}

extern "C" void kernel_launch(void* const* d_in, const int* in_sizes, int n_in,
                              void* d_out, int out_size, void* d_ws, size_t ws_size,
                              hipStream_t stream) {
    const float* lbl = (const float*)d_in[0];
    const float* pred = (const float*)d_in[1];
    u16* zb = (u16*)d_ws;
    float* xnorm = (float*)((char*)d_ws + (size_t)ZROWS * DIM * 2);
    float* partials = (float*)((char*)d_ws + (size_t)ZROWS * DIM * 2 + (size_t)ZROWS * 4);

    prep_kernel<<<ZROWS / 4, 256, 0, stream>>>(lbl, pred, zb, xnorm);
    mmd_gemm_kernel<<<NBLOCKS, 256, 0, stream>>>(zb, xnorm, partials);
    reduce_kernel<<<1, 256, 0, stream>>>(partials, (float*)d_out, NBLOCKS);
}